// Round 14
// baseline (328.140 us; speedup 1.0000x reference)
//
#include <hip/hip_runtime.h>
#include <hip/hip_bf16.h>

typedef __bf16 bf16;
typedef bf16 bf16x2 __attribute__((ext_vector_type(2)));
typedef bf16 bf16x4 __attribute__((ext_vector_type(4)));
typedef bf16 bf16x8 __attribute__((ext_vector_type(8)));
typedef float floatx4 __attribute__((ext_vector_type(4)));

#define MFMA_BF16(a, b, c) __builtin_amdgcn_mfma_f32_16x16x32_bf16((a), (b), (c), 0, 0, 0)

// Async global->LDS DMA, 16 B per lane. LDS dest = uniform base + lane*16B
// (hardware rule, learn_hip m104); global src is per-lane.
__device__ __forceinline__ void gload16(const bf16* gsrc, bf16* ldst) {
    __builtin_amdgcn_global_load_lds(
        (__attribute__((address_space(1))) void*)const_cast<bf16*>(gsrc),
        (__attribute__((address_space(3))) void*)ldst,
        16, 0, 0);
}

// ---------------------------------------------------------------------------
// MERGED prep + zeroing (memsets folded in as block ranges):
//   blocks 0..4095     : cvt x/ctx -> bf16 (8 els/thread)
//   blocks 4096..7167  : weight transpose (Wq 1024 tiles, Wkv 2048 tiles)
//   blocks 7168..11263 : zero `out` (float4 stores)
//   blocks 11264..11327: zero `L`
// ---------------------------------------------------------------------------
__global__ __launch_bounds__(256) void prep_kernel(const float* __restrict__ x,
                                                   const float* __restrict__ ctx,
                                                   const float* __restrict__ Wq,
                                                   const float* __restrict__ Wkv,
                                                   bf16* __restrict__ xb,
                                                   bf16* __restrict__ cb,
                                                   bf16* __restrict__ WqT,
                                                   bf16* __restrict__ WkvT,
                                                   float* __restrict__ out,
                                                   float* __restrict__ L) {
    __shared__ float tile[32][33];
    const int t = threadIdx.x;
    int blk = blockIdx.x;
    if (blk >= 7168) {                      // ---- zeroing tasks ----
        if (blk < 11264) {                  // out: 4096 blocks * 256 * 4 floats
            int idx = (blk - 7168) * 256 + t;
            ((float4*)out)[idx] = make_float4(0.f, 0.f, 0.f, 0.f);
        } else {                            // L: 64 blocks * 256 * 4 floats
            int idx = (blk - 11264) * 256 + t;
            ((float4*)L)[idx] = make_float4(0.f, 0.f, 0.f, 0.f);
        }
        return;
    }
    if (blk < 4096) {                       // ---- cvt task ----
        int idx = blk * 256 + t;
        const float* in; bf16* outp;
        if (idx < 524288) { in = x; outp = xb; }
        else              { in = ctx; outp = cb; idx -= 524288; }
        const float* src = in + (size_t)idx * 8;
        float4 f0 = *(const float4*)src;
        float4 f1 = *(const float4*)(src + 4);
        bf16x8 v = {(bf16)f0.x, (bf16)f0.y, (bf16)f0.z, (bf16)f0.w,
                    (bf16)f1.x, (bf16)f1.y, (bf16)f1.z, (bf16)f1.w};
        *(bf16x8*)(outp + (size_t)idx * 8) = v;
        return;
    }
    blk -= 4096;                            // ---- transpose task ----
    const float* in; bf16* outp; int R, C, bx, by;
    if (blk < 1024) { in = Wq;  outp = WqT;  R = 1024; C = 1024; bx = blk & 31; by = blk >> 5; }
    else { blk -= 1024; in = Wkv; outp = WkvT; R = 1024; C = 2048; bx = blk & 63; by = blk >> 6; }
    const int r0 = by * 32, c0 = bx * 32;
    int r = t >> 3, c4 = (t & 7) * 4;
    float4 v = *(const float4*)&in[(size_t)(r0 + r) * C + c0 + c4];
    tile[r][c4 + 0] = v.x; tile[r][c4 + 1] = v.y;
    tile[r][c4 + 2] = v.z; tile[r][c4 + 3] = v.w;
    __syncthreads();
    int rp = t >> 3, cp = (t & 7) * 4;
    bf16x4 w = {(bf16)tile[cp + 0][rp], (bf16)tile[cp + 1][rp],
                (bf16)tile[cp + 2][rp], (bf16)tile[cp + 3][rp]};
    *(bf16x4*)&outp[(size_t)(c0 + rp) * R + r0 + cp] = w;
}

// ---------------------------------------------------------------------------
// MERGED GEMM with FUSED V-TRANSPOSE EPILOGUE — R13-identical (measured).
// ---------------------------------------------------------------------------
__global__ __launch_bounds__(256) void gemm_all(const bf16* __restrict__ xb,
                                                const bf16* __restrict__ cb,
                                                const bf16* __restrict__ WqT,
                                                const bf16* __restrict__ WkvT,
                                                bf16* __restrict__ Qb,
                                                bf16* __restrict__ Kb,
                                                bf16* __restrict__ Vt) {
    __shared__ bf16 As[128 * 32];
    __shared__ bf16 Bs[128 * 32];
    __shared__ __align__(16) bf16 Ts[64 * 136];   // [hd_local][j + 8 pad]
    const int t = threadIdx.x;
    const int wv = t >> 6, lane = t & 63, quad = lane >> 4, l15 = lane & 15;
    const int wr = wv >> 1, wc = wv & 1;
    unsigned nb = blockIdx.x;
    unsigned o = (nb & 7) * 96 + (nb >> 3);
    const bf16 *A, *B; bool kv; int bx, by;
    if (o < 256) { A = xb; B = WqT; kv = false; bx = o & 7; by = o >> 3; }
    else { unsigned ob = o - 256; A = cb; B = WkvT; kv = true; bx = ob & 15; by = ob >> 4; }
    const int m0 = by * 128, n0 = bx * 128;
    const int srow = lane >> 2, scol = (lane & 3) * 8;   // staging lane geometry

    floatx4 acc[4][4] = {};

    for (int k0 = 0; k0 < 1024; k0 += 32) {
        __syncthreads();          // previous iter's LDS reads complete
#pragma unroll
        for (int ri = 0; ri < 2; ++ri) {
            const int rb = (ri * 4 + wv) * 16;            // uniform per wave
            gload16(&A[(size_t)(m0 + rb + srow) * 1024 + k0 + scol], &As[rb * 32]);
            gload16(&B[(size_t)(n0 + rb + srow) * 1024 + k0 + scol], &Bs[rb * 32]);
        }
        __syncthreads();          // drains vmcnt(0): tiles ready
        bf16x8 af[4], bfr[4];
#pragma unroll
        for (int mt = 0; mt < 4; ++mt)
            af[mt] = *(bf16x8*)&As[(wr * 64 + mt * 16 + l15) * 32 + quad * 8];
#pragma unroll
        for (int nt = 0; nt < 4; ++nt)
            bfr[nt] = *(bf16x8*)&Bs[(wc * 64 + nt * 16 + l15) * 32 + quad * 8];
#pragma unroll
        for (int mt = 0; mt < 4; ++mt)
#pragma unroll
            for (int nt = 0; nt < 4; ++nt)
                acc[mt][nt] = MFMA_BF16(af[mt], bfr[nt], acc[mt][nt]);
    }

    if (!kv || n0 < 1024) {
        bf16* C = kv ? Kb : Qb;
#pragma unroll
        for (int mt = 0; mt < 4; ++mt)
#pragma unroll
            for (int nt = 0; nt < 4; ++nt)
#pragma unroll
                for (int r = 0; r < 4; ++r) {
                    int m = m0 + wr * 64 + mt * 16 + quad * 4 + r;
                    int n = n0 + wc * 64 + nt * 16 + l15;
                    C[(size_t)m * 1024 + n] = (bf16)acc[mt][nt][r];
                }
    } else {
        const int b = m0 >> 10, j0 = m0 & 1023, hd0 = n0 - 1024;
#pragma unroll
        for (int half = 0; half < 2; ++half) {
            __syncthreads();                    // seal prior Ts reads
            if (wc == half) {
#pragma unroll
                for (int mt = 0; mt < 4; ++mt)
#pragma unroll
                    for (int nt = 0; nt < 4; ++nt) {
                        int hdl = nt * 16 + l15;
                        int jl  = wr * 64 + mt * 16 + quad * 4;
                        bf16x4 p = {(bf16)acc[mt][nt][0], (bf16)acc[mt][nt][1],
                                    (bf16)acc[mt][nt][2], (bf16)acc[mt][nt][3]};
                        *(bf16x4*)&Ts[hdl * 136 + jl] = p;
                    }
            }
            __syncthreads();                    // Ts ready
#pragma unroll
            for (int k = 0; k < 4; ++k) {
                int idx = t + 256 * k;
                int row = idx >> 4, c8 = idx & 15;
                bf16x8 v = *(bf16x8*)&Ts[row * 136 + c8 * 8];
                *(bf16x8*)&Vt[(size_t)(b * 1024 + hd0 + half * 64 + row) * 1024 +
                              j0 + c8 * 8] = v;
            }
        }
    }
}

// ---------------------------------------------------------------------------
// MERGED denom + prep_wt — R13-identical.
// ---------------------------------------------------------------------------
__global__ __launch_bounds__(256, 4) void dv_kernel(const bf16* __restrict__ Qb,
                                                    const bf16* __restrict__ Kb,
                                                    float* __restrict__ L,
                                                    const float* __restrict__ Wt,
                                                    bf16* __restrict__ WtcT) {
    const int t = threadIdx.x;
    if (blockIdx.x == 2048) {                // ---- prep_wt task ----
        const int g = t >> 4, k = t & 15;
        float s = 0.f;
#pragma unroll
        for (int gg = 0; gg < 16; ++gg) s += Wt[k * 16 + gg];
        WtcT[g * 32 + k] = (bf16)(Wt[k * 16 + g] - s * 0.0625f);
        WtcT[g * 32 + 16 + k] = (bf16)0.f;
        return;
    }
    // ---- denom task ----
    const int wv = t >> 6, lane = t & 63, quad = lane >> 4, l15 = lane & 15;
    unsigned n = blockIdx.x;                               // 0..2047
    unsigned o = (n & 7) * 256 + (n >> 3);
    const int i0 = (o & 31) * 32;
    const int b  = (o >> 5) & 3;
    const int jz = o >> 7;
    const float scale = 0.125f;
    const bf16* Kbase = Kb + (size_t)b * 1024 * 1024;

    for (int hh = 0; hh < 4; ++hh) {
        const int h = wv * 4 + hh;
        bf16x8 qa[2][2];
#pragma unroll
        for (int it = 0; it < 2; ++it) {
            const bf16* qp = Qb + (size_t)(b * 1024 + i0 + it * 16 + l15) * 1024 +
                             h * 64 + quad * 8;
            qa[it][0] = *(const bf16x8*)qp;
            qa[it][1] = *(const bf16x8*)(qp + 32);
        }
        floatx4 se[2] = {};
#pragma unroll
        for (int jt = 0; jt < 4; ++jt) {
            int j = jz * 64 + jt * 16 + l15;
            const bf16* kp = Kbase + (size_t)j * 1024 + h * 64 + quad * 8;
            bf16x8 k0 = *(const bf16x8*)kp;
            bf16x8 k1 = *(const bf16x8*)(kp + 32);
#pragma unroll
            for (int it = 0; it < 2; ++it) {
                floatx4 c = {0.f, 0.f, 0.f, 0.f};
                c = MFMA_BF16(qa[it][0], k0, c);
                c = MFMA_BF16(qa[it][1], k1, c);
#pragma unroll
                for (int r = 0; r < 4; ++r) se[it][r] += __expf(c[r] * scale);
            }
        }
#pragma unroll
        for (int it = 0; it < 2; ++it)
#pragma unroll
            for (int r = 0; r < 4; ++r) {
                float s = se[it][r];
                s += __shfl_xor(s, 1); s += __shfl_xor(s, 2);
                s += __shfl_xor(s, 4); s += __shfl_xor(s, 8);
                if (l15 == 0)
                    atomicAdd(&L[(size_t)(b * 16 + h) * 1024 + i0 + it * 16 +
                                 quad * 4 + r], s);
            }
    }
}

// ---------------------------------------------------------------------------
// Main fused attention — WIDE-J variant: j-tile 64 (was 32), jt count 8
// (was 16), 16 barriers/block (was 32). Decisive test of the phase-latency
// theory: 2x work per phase amortizes each convoy/L2-latency exposure.
// grid (64,4,2), 512 thr, XCD swizzle. Occupancy stays 2 blocks/CU
// (register-capped), LDS 77840 B fits 2/CU.
// Buf1 [p=i*64+jl][16h+4pad] = 40960 B; Buf2 [g][i*72 + jl] stride 1152
// = 36864 B; Zbuf separate.
// ---------------------------------------------------------------------------
__global__ __launch_bounds__(512, 4) void attn_kernel(const bf16* __restrict__ Qb,
                                                      const bf16* __restrict__ Kb,
                                                      const bf16* __restrict__ Vt,
                                                      const float* __restrict__ L,
                                                      const bf16* __restrict__ WtcT,
                                                      const float* __restrict__ gamma,
                                                      const float* __restrict__ beta,
                                                      float* __restrict__ out) {
    __shared__ bf16 Buf1[1024 * 20];       // [point p=i*64+jl][16 h + 4 pad]
    __shared__ bf16 Buf2[16 * 1152];       // [g][i*72 + jl]
    __shared__ __align__(16) bf16 Zbuf[8];
    const int t = threadIdx.x;
    const int wv = t >> 6, lane = t & 63, quad = lane >> 4, l15 = lane & 15;
    unsigned n = blockIdx.x + (blockIdx.y << 6) + (blockIdx.z << 8);   // 512 total
    unsigned o_idx = (n & 7) * 64 + (n >> 3);
    const int i0 = (o_idx & 63) * 16;
    const int b  = (o_idx >> 6) & 3;
    const int jz = o_idx >> 8;
    const float scale = 0.125f;

    if (t < 8) Zbuf[t] = (bf16)0.f;

    bf16x8 a_wt = *(const bf16x8*)&WtcT[l15 * 32 + quad * 8];
    float gq[4], bq[4];
#pragma unroll
    for (int r = 0; r < 4; ++r) { gq[r] = gamma[quad * 4 + r]; bq[r] = beta[quad * 4 + r]; }

    bf16x8 qa[2][2];
    float invl[2][4];
#pragma unroll
    for (int hh = 0; hh < 2; ++hh) {
        int h = wv * 2 + hh;
        const bf16* qp = Qb + (size_t)(b * 1024 + i0 + l15) * 1024 + h * 64 + quad * 8;
        qa[hh][0] = *(const bf16x8*)qp;
        qa[hh][1] = *(const bf16x8*)(qp + 32);
#pragma unroll
        for (int r = 0; r < 4; ++r)
            invl[hh][r] = 1.f / L[(size_t)(b * 16 + h) * 1024 + i0 + quad * 4 + r];
    }

    const bf16* Kbase = Kb + (size_t)b * 1024 * 1024;
    const bf16* Vbase = Vt + (size_t)b * 16 * 64 * 1024;
    floatx4 o[2][4] = {};

    for (int jt = 0; jt < 8; ++jt) {
        const int j0 = jz * 512 + jt * 64;
        // (a) S: 4 x 16 j-rows -> w=exp*invl -> Buf1
#pragma unroll
        for (int ns = 0; ns < 4; ++ns) {
            floatx4 cw[2];
#pragma unroll
            for (int hh = 0; hh < 2; ++hh) {
                int h = wv * 2 + hh;
                const bf16* kp = Kbase + (size_t)(j0 + ns * 16 + l15) * 1024 + h * 64 + quad * 8;
                floatx4 c = {0.f, 0.f, 0.f, 0.f};
                c = MFMA_BF16(qa[hh][0], *(const bf16x8*)kp, c);
                c = MFMA_BF16(qa[hh][1], *(const bf16x8*)(kp + 32), c);
                cw[hh] = c;
            }
#pragma unroll
            for (int r = 0; r < 4; ++r) {
                bf16x2 pk = {(bf16)(__expf(cw[0][r] * scale) * invl[0][r]),
                             (bf16)(__expf(cw[1][r] * scale) * invl[1][r])};
                *(bf16x2*)&Buf1[((quad * 4 + r) * 64 + ns * 16 + l15) * 20 + wv * 2] = pk;
            }
        }
        __syncthreads();
        // (b) mix + LN: 64 point-groups, pg = wv*8+grp; i = pg>>2, jb = (pg&3)*16
#pragma unroll
        for (int grp = 0; grp < 8; ++grp) {
            int pg = wv * 8 + grp;
            int p = pg * 16 + l15;
            const bf16* src = (quad < 2) ? &Buf1[p * 20 + quad * 8] : Zbuf;
            floatx4 c = {0.f, 0.f, 0.f, 0.f};
            c = MFMA_BF16(a_wt, *(const bf16x8*)src, c);
            float s2 = c[0] * c[0] + c[1] * c[1] + c[2] * c[2] + c[3] * c[3];
            s2 += __shfl_xor(s2, 16);
            s2 += __shfl_xor(s2, 32);
            float rs = rsqrtf(s2 * 0.0625f + 1e-5f);
            int ib = pg >> 2, jb = (pg & 3) * 16;
#pragma unroll
            for (int r = 0; r < 4; ++r) {
                float w2 = c[r] * rs * gq[r] + bq[r];
                Buf2[(quad * 4 + r) * 1152 + ib * 72 + jb + l15] = (bf16)w2;
            }
        }
        __syncthreads();
        // (c) PV over two 32-wide j-halves
#pragma unroll
        for (int js = 0; js < 2; ++js) {
#pragma unroll
            for (int hh = 0; hh < 2; ++hh) {
                int g = wv * 2 + hh;
                bf16x8 a = *(bf16x8*)&Buf2[g * 1152 + l15 * 72 + js * 32 + quad * 8];
#pragma unroll
                for (int dt = 0; dt < 4; ++dt) {
                    const bf16* vp = Vbase + (size_t)(g * 64 + dt * 16 + l15) * 1024 +
                                     j0 + js * 32 + quad * 8;
                    o[hh][dt] = MFMA_BF16(a, *(const bf16x8*)vp, o[hh][dt]);
                }
            }
        }
    }
#pragma unroll
    for (int hh = 0; hh < 2; ++hh) {
        int g = wv * 2 + hh;
#pragma unroll
        for (int dt = 0; dt < 4; ++dt)
#pragma unroll
            for (int r = 0; r < 4; ++r)
                atomicAdd(&out[(size_t)(b * 1024 + i0 + quad * 4 + r) * 1024 +
                               g * 64 + dt * 16 + l15], o[hh][dt][r]);
    }
}

extern "C" void kernel_launch(void* const* d_in, const int* in_sizes, int n_in,
                              void* d_out, int out_size, void* d_ws, size_t ws_size,
                              hipStream_t stream) {
    const float* x     = (const float*)d_in[0];
    const float* ctx   = (const float*)d_in[1];
    const float* Wq    = (const float*)d_in[2];
    const float* Wkv   = (const float*)d_in[3];
    const float* Wt    = (const float*)d_in[4];
    const float* gamma = (const float*)d_in[5];
    const float* beta  = (const float*)d_in[6];
    float* out = (float*)d_out;

    // ws layout (bf16 els): xb 4M | ctxb 4M | WqT 1M | WkvT 2M | Qb 4M | Kb 4M |
    //                       Vt 4M | L (64K fp32) | WtcT (512 bf16)
    bf16* xb   = (bf16*)d_ws;
    bf16* cb   = xb + (size_t)4 * 1024 * 1024;
    bf16* WqT  = cb + (size_t)4 * 1024 * 1024;
    bf16* WkvT = WqT + (size_t)1024 * 1024;
    bf16* Qb   = WkvT + (size_t)2048 * 1024;
    bf16* Kb   = Qb + (size_t)4 * 1024 * 1024;
    bf16* Vt   = Kb + (size_t)4 * 1024 * 1024;
    float* L   = (float*)(Vt + (size_t)4 * 1024 * 1024);
    bf16* WtcT = (bf16*)(L + (size_t)4 * 16 * 1024);

    prep_kernel<<<11328, 256, 0, stream>>>(x, ctx, Wq, Wkv, xb, cb, WqT, WkvT, out, L);
    gemm_all<<<768, 256, 0, stream>>>(xb, cb, WqT, WkvT, Qb, Kb, Vt);
    dv_kernel<<<2049, 256, 0, stream>>>(Qb, Kb, L, Wt, WtcT);
    attn_kernel<<<dim3(64, 4, 2), 512, 0, stream>>>(Qb, Kb, Vt, L, WtcT, gamma, beta, out);
}

// Round 15
// 322.627 us; speedup vs baseline: 1.0171x; 1.0171x over previous
//
#include <hip/hip_runtime.h>
#include <hip/hip_bf16.h>

typedef __bf16 bf16;
typedef bf16 bf16x2 __attribute__((ext_vector_type(2)));
typedef bf16 bf16x4 __attribute__((ext_vector_type(4)));
typedef bf16 bf16x8 __attribute__((ext_vector_type(8)));
typedef float floatx4 __attribute__((ext_vector_type(4)));

#define MFMA_BF16(a, b, c) __builtin_amdgcn_mfma_f32_16x16x32_bf16((a), (b), (c), 0, 0, 0)

// Async global->LDS DMA, 16 B per lane. LDS dest = uniform base + lane*16B
// (hardware rule, learn_hip m104); global src is per-lane.
__device__ __forceinline__ void gload16(const bf16* gsrc, bf16* ldst) {
    __builtin_amdgcn_global_load_lds(
        (__attribute__((address_space(1))) void*)const_cast<bf16*>(gsrc),
        (__attribute__((address_space(3))) void*)ldst,
        16, 0, 0);
}

// ---------------------------------------------------------------------------
// MERGED prep + zeroing (memsets folded in as block ranges):
//   blocks 0..4095     : cvt x/ctx -> bf16 (8 els/thread)
//   blocks 4096..7167  : weight transpose (Wq 1024 tiles, Wkv 2048 tiles)
//   blocks 7168..11263 : zero `out` (float4 stores)
//   blocks 11264..11327: zero `L`
// ---------------------------------------------------------------------------
__global__ __launch_bounds__(256) void prep_kernel(const float* __restrict__ x,
                                                   const float* __restrict__ ctx,
                                                   const float* __restrict__ Wq,
                                                   const float* __restrict__ Wkv,
                                                   bf16* __restrict__ xb,
                                                   bf16* __restrict__ cb,
                                                   bf16* __restrict__ WqT,
                                                   bf16* __restrict__ WkvT,
                                                   float* __restrict__ out,
                                                   float* __restrict__ L) {
    __shared__ float tile[32][33];
    const int t = threadIdx.x;
    int blk = blockIdx.x;
    if (blk >= 7168) {                      // ---- zeroing tasks ----
        if (blk < 11264) {                  // out: 4096 blocks * 256 * 4 floats
            int idx = (blk - 7168) * 256 + t;
            ((float4*)out)[idx] = make_float4(0.f, 0.f, 0.f, 0.f);
        } else {                            // L: 64 blocks * 256 * 4 floats
            int idx = (blk - 11264) * 256 + t;
            ((float4*)L)[idx] = make_float4(0.f, 0.f, 0.f, 0.f);
        }
        return;
    }
    if (blk < 4096) {                       // ---- cvt task ----
        int idx = blk * 256 + t;
        const float* in; bf16* outp;
        if (idx < 524288) { in = x; outp = xb; }
        else              { in = ctx; outp = cb; idx -= 524288; }
        const float* src = in + (size_t)idx * 8;
        float4 f0 = *(const float4*)src;
        float4 f1 = *(const float4*)(src + 4);
        bf16x8 v = {(bf16)f0.x, (bf16)f0.y, (bf16)f0.z, (bf16)f0.w,
                    (bf16)f1.x, (bf16)f1.y, (bf16)f1.z, (bf16)f1.w};
        *(bf16x8*)(outp + (size_t)idx * 8) = v;
        return;
    }
    blk -= 4096;                            // ---- transpose task ----
    const float* in; bf16* outp; int R, C, bx, by;
    if (blk < 1024) { in = Wq;  outp = WqT;  R = 1024; C = 1024; bx = blk & 31; by = blk >> 5; }
    else { blk -= 1024; in = Wkv; outp = WkvT; R = 1024; C = 2048; bx = blk & 63; by = blk >> 6; }
    const int r0 = by * 32, c0 = bx * 32;
    int r = t >> 3, c4 = (t & 7) * 4;
    float4 v = *(const float4*)&in[(size_t)(r0 + r) * C + c0 + c4];
    tile[r][c4 + 0] = v.x; tile[r][c4 + 1] = v.y;
    tile[r][c4 + 2] = v.z; tile[r][c4 + 3] = v.w;
    __syncthreads();
    int rp = t >> 3, cp = (t & 7) * 4;
    bf16x4 w = {(bf16)tile[cp + 0][rp], (bf16)tile[cp + 1][rp],
                (bf16)tile[cp + 2][rp], (bf16)tile[cp + 3][rp]};
    *(bf16x4*)&outp[(size_t)(c0 + rp) * R + r0 + cp] = w;
}

// ---------------------------------------------------------------------------
// MERGED GEMM with FUSED V-TRANSPOSE EPILOGUE — R13-identical (measured).
// ---------------------------------------------------------------------------
__global__ __launch_bounds__(256) void gemm_all(const bf16* __restrict__ xb,
                                                const bf16* __restrict__ cb,
                                                const bf16* __restrict__ WqT,
                                                const bf16* __restrict__ WkvT,
                                                bf16* __restrict__ Qb,
                                                bf16* __restrict__ Kb,
                                                bf16* __restrict__ Vt) {
    __shared__ bf16 As[128 * 32];
    __shared__ bf16 Bs[128 * 32];
    __shared__ __align__(16) bf16 Ts[64 * 136];   // [hd_local][j + 8 pad]
    const int t = threadIdx.x;
    const int wv = t >> 6, lane = t & 63, quad = lane >> 4, l15 = lane & 15;
    const int wr = wv >> 1, wc = wv & 1;
    unsigned nb = blockIdx.x;
    unsigned o = (nb & 7) * 96 + (nb >> 3);
    const bf16 *A, *B; bool kv; int bx, by;
    if (o < 256) { A = xb; B = WqT; kv = false; bx = o & 7; by = o >> 3; }
    else { unsigned ob = o - 256; A = cb; B = WkvT; kv = true; bx = ob & 15; by = ob >> 4; }
    const int m0 = by * 128, n0 = bx * 128;
    const int srow = lane >> 2, scol = (lane & 3) * 8;   // staging lane geometry

    floatx4 acc[4][4] = {};

    for (int k0 = 0; k0 < 1024; k0 += 32) {
        __syncthreads();          // previous iter's LDS reads complete
#pragma unroll
        for (int ri = 0; ri < 2; ++ri) {
            const int rb = (ri * 4 + wv) * 16;            // uniform per wave
            gload16(&A[(size_t)(m0 + rb + srow) * 1024 + k0 + scol], &As[rb * 32]);
            gload16(&B[(size_t)(n0 + rb + srow) * 1024 + k0 + scol], &Bs[rb * 32]);
        }
        __syncthreads();          // drains vmcnt(0): tiles ready
        bf16x8 af[4], bfr[4];
#pragma unroll
        for (int mt = 0; mt < 4; ++mt)
            af[mt] = *(bf16x8*)&As[(wr * 64 + mt * 16 + l15) * 32 + quad * 8];
#pragma unroll
        for (int nt = 0; nt < 4; ++nt)
            bfr[nt] = *(bf16x8*)&Bs[(wc * 64 + nt * 16 + l15) * 32 + quad * 8];
#pragma unroll
        for (int mt = 0; mt < 4; ++mt)
#pragma unroll
            for (int nt = 0; nt < 4; ++nt)
                acc[mt][nt] = MFMA_BF16(af[mt], bfr[nt], acc[mt][nt]);
    }

    if (!kv || n0 < 1024) {
        bf16* C = kv ? Kb : Qb;
#pragma unroll
        for (int mt = 0; mt < 4; ++mt)
#pragma unroll
            for (int nt = 0; nt < 4; ++nt)
#pragma unroll
                for (int r = 0; r < 4; ++r) {
                    int m = m0 + wr * 64 + mt * 16 + quad * 4 + r;
                    int n = n0 + wc * 64 + nt * 16 + l15;
                    C[(size_t)m * 1024 + n] = (bf16)acc[mt][nt][r];
                }
    } else {
        const int b = m0 >> 10, j0 = m0 & 1023, hd0 = n0 - 1024;
#pragma unroll
        for (int half = 0; half < 2; ++half) {
            __syncthreads();                    // seal prior Ts reads
            if (wc == half) {
#pragma unroll
                for (int mt = 0; mt < 4; ++mt)
#pragma unroll
                    for (int nt = 0; nt < 4; ++nt) {
                        int hdl = nt * 16 + l15;
                        int jl  = wr * 64 + mt * 16 + quad * 4;
                        bf16x4 p = {(bf16)acc[mt][nt][0], (bf16)acc[mt][nt][1],
                                    (bf16)acc[mt][nt][2], (bf16)acc[mt][nt][3]};
                        *(bf16x4*)&Ts[hdl * 136 + jl] = p;
                    }
            }
            __syncthreads();                    // Ts ready
#pragma unroll
            for (int k = 0; k < 4; ++k) {
                int idx = t + 256 * k;
                int row = idx >> 4, c8 = idx & 15;
                bf16x8 v = *(bf16x8*)&Ts[row * 136 + c8 * 8];
                *(bf16x8*)&Vt[(size_t)(b * 1024 + hd0 + half * 64 + row) * 1024 +
                              j0 + c8 * 8] = v;
            }
        }
    }
}

// ---------------------------------------------------------------------------
// MERGED denom + prep_wt — R13-identical.
// ---------------------------------------------------------------------------
__global__ __launch_bounds__(256, 4) void dv_kernel(const bf16* __restrict__ Qb,
                                                    const bf16* __restrict__ Kb,
                                                    float* __restrict__ L,
                                                    const float* __restrict__ Wt,
                                                    bf16* __restrict__ WtcT) {
    const int t = threadIdx.x;
    if (blockIdx.x == 2048) {                // ---- prep_wt task ----
        const int g = t >> 4, k = t & 15;
        float s = 0.f;
#pragma unroll
        for (int gg = 0; gg < 16; ++gg) s += Wt[k * 16 + gg];
        WtcT[g * 32 + k] = (bf16)(Wt[k * 16 + g] - s * 0.0625f);
        WtcT[g * 32 + 16 + k] = (bf16)0.f;
        return;
    }
    // ---- denom task ----
    const int wv = t >> 6, lane = t & 63, quad = lane >> 4, l15 = lane & 15;
    unsigned n = blockIdx.x;                               // 0..2047
    unsigned o = (n & 7) * 256 + (n >> 3);
    const int i0 = (o & 31) * 32;
    const int b  = (o >> 5) & 3;
    const int jz = o >> 7;
    const float scale = 0.125f;
    const bf16* Kbase = Kb + (size_t)b * 1024 * 1024;

    for (int hh = 0; hh < 4; ++hh) {
        const int h = wv * 4 + hh;
        bf16x8 qa[2][2];
#pragma unroll
        for (int it = 0; it < 2; ++it) {
            const bf16* qp = Qb + (size_t)(b * 1024 + i0 + it * 16 + l15) * 1024 +
                             h * 64 + quad * 8;
            qa[it][0] = *(const bf16x8*)qp;
            qa[it][1] = *(const bf16x8*)(qp + 32);
        }
        floatx4 se[2] = {};
#pragma unroll
        for (int jt = 0; jt < 4; ++jt) {
            int j = jz * 64 + jt * 16 + l15;
            const bf16* kp = Kbase + (size_t)j * 1024 + h * 64 + quad * 8;
            bf16x8 k0 = *(const bf16x8*)kp;
            bf16x8 k1 = *(const bf16x8*)(kp + 32);
#pragma unroll
            for (int it = 0; it < 2; ++it) {
                floatx4 c = {0.f, 0.f, 0.f, 0.f};
                c = MFMA_BF16(qa[it][0], k0, c);
                c = MFMA_BF16(qa[it][1], k1, c);
#pragma unroll
                for (int r = 0; r < 4; ++r) se[it][r] += __expf(c[r] * scale);
            }
        }
#pragma unroll
        for (int it = 0; it < 2; ++it)
#pragma unroll
            for (int r = 0; r < 4; ++r) {
                float s = se[it][r];
                s += __shfl_xor(s, 1); s += __shfl_xor(s, 2);
                s += __shfl_xor(s, 4); s += __shfl_xor(s, 8);
                if (l15 == 0)
                    atomicAdd(&L[(size_t)(b * 16 + h) * 1024 + i0 + it * 16 +
                                 quad * 4 + r], s);
            }
    }
}

// ---------------------------------------------------------------------------
// Main fused attention — R13-identical structure (measured 148.9 us) plus
// T5 s_setprio(1) around the MFMA clusters. Mechanism: 2 independent blocks
// per CU drift out of phase; setprio lets the scheduler prefer the block in
// its MFMA burst over the other block's load/exp phase (m191: attn +4-7%).
// grid (64,4,2), 512 thr, 2 barriers/jt, LDS 40960 (rot-640 Buf2, zero-hole),
// XCD swizzle. VGPR 60 / SGPR 48, no spills.
// ---------------------------------------------------------------------------
__global__ __launch_bounds__(512, 4) void attn_kernel(const bf16* __restrict__ Qb,
                                                      const bf16* __restrict__ Kb,
                                                      const bf16* __restrict__ Vt,
                                                      const float* __restrict__ L,
                                                      const bf16* __restrict__ WtcT,
                                                      const float* __restrict__ gamma,
                                                      const float* __restrict__ beta,
                                                      float* __restrict__ out) {
    __shared__ bf16 Buf1[512 * 20];        // [point p=i*32+jl][16 h + 4 pad]
    __shared__ bf16 Buf2[16 * 640];        // [g][rot(g) + i*40 + jl]
    const int t = threadIdx.x;
    const int wv = t >> 6, lane = t & 63, quad = lane >> 4, l15 = lane & 15;
    unsigned n = blockIdx.x + (blockIdx.y << 6) + (blockIdx.z << 8);   // 512 total
    unsigned o_idx = (n & 7) * 64 + (n >> 3);
    const int i0 = (o_idx & 63) * 16;
    const int b  = (o_idx >> 6) & 3;
    const int jz = o_idx >> 8;
    const float scale = 0.125f;

    if (t < 8) Buf2[2560 + t] = (bf16)0.f;   // zero region in the rot-hole
    const bf16* Zbuf = &Buf2[2560];

    bf16x8 a_wt = *(const bf16x8*)&WtcT[l15 * 32 + quad * 8];
    float gq[4], bq[4];
#pragma unroll
    for (int r = 0; r < 4; ++r) { gq[r] = gamma[quad * 4 + r]; bq[r] = beta[quad * 4 + r]; }

    bf16x8 qa[2][2];
    float invl[2][4];
#pragma unroll
    for (int hh = 0; hh < 2; ++hh) {
        int h = wv * 2 + hh;
        const bf16* qp = Qb + (size_t)(b * 1024 + i0 + l15) * 1024 + h * 64 + quad * 8;
        qa[hh][0] = *(const bf16x8*)qp;
        qa[hh][1] = *(const bf16x8*)(qp + 32);
#pragma unroll
        for (int r = 0; r < 4; ++r)
            invl[hh][r] = 1.f / L[(size_t)(b * 16 + h) * 1024 + i0 + quad * 4 + r];
    }

    const bf16* Kbase = Kb + (size_t)b * 1024 * 1024;
    const bf16* Vbase = Vt + (size_t)b * 16 * 64 * 1024;
    floatx4 o[2][4] = {};

    for (int jt = 0; jt < 16; ++jt) {
        const int j0 = jz * 512 + jt * 32;
#pragma unroll
        for (int ns = 0; ns < 2; ++ns) {
            floatx4 cw[2];
            __builtin_amdgcn_s_setprio(1);
#pragma unroll
            for (int hh = 0; hh < 2; ++hh) {
                int h = wv * 2 + hh;
                const bf16* kp = Kbase + (size_t)(j0 + ns * 16 + l15) * 1024 + h * 64 + quad * 8;
                floatx4 c = {0.f, 0.f, 0.f, 0.f};
                c = MFMA_BF16(qa[hh][0], *(const bf16x8*)kp, c);
                c = MFMA_BF16(qa[hh][1], *(const bf16x8*)(kp + 32), c);
                cw[hh] = c;
            }
            __builtin_amdgcn_s_setprio(0);
#pragma unroll
            for (int r = 0; r < 4; ++r) {
                bf16x2 pk = {(bf16)(__expf(cw[0][r] * scale) * invl[0][r]),
                             (bf16)(__expf(cw[1][r] * scale) * invl[1][r])};
                *(bf16x2*)&Buf1[((quad * 4 + r) * 32 + ns * 16 + l15) * 20 + wv * 2] = pk;
            }
        }
        __syncthreads();
#pragma unroll
        for (int grp = 0; grp < 4; ++grp) {
            int gi = wv * 4 + grp, ig = gi >> 1, jb = (gi & 1) * 16;
            int p = ig * 32 + jb + l15;
            const bf16* src = (quad < 2) ? &Buf1[p * 20 + quad * 8] : Zbuf;
            floatx4 c = {0.f, 0.f, 0.f, 0.f};
            c = MFMA_BF16(a_wt, *(const bf16x8*)src, c);
            float s2 = c[0] * c[0] + c[1] * c[1] + c[2] * c[2] + c[3] * c[3];
            s2 += __shfl_xor(s2, 16);
            s2 += __shfl_xor(s2, 32);
            float rs = rsqrtf(s2 * 0.0625f + 1e-5f);
#pragma unroll
            for (int r = 0; r < 4; ++r) {
                float w2 = c[r] * rs * gq[r] + bq[r];
                Buf2[(quad * 4 + r) * 640 + (quad & 1) * 8 + ig * 40 + jb + l15] = (bf16)w2;
            }
        }
        __syncthreads();
        __builtin_amdgcn_s_setprio(1);
#pragma unroll
        for (int hh = 0; hh < 2; ++hh) {
            int g = wv * 2 + hh;
            bf16x8 a = *(bf16x8*)&Buf2[g * 640 + ((g >> 2) & 1) * 8 + l15 * 40 + quad * 8];
#pragma unroll
            for (int dt = 0; dt < 4; ++dt) {
                const bf16* vp = Vbase + (size_t)(g * 64 + dt * 16 + l15) * 1024 + j0 + quad * 8;
                o[hh][dt] = MFMA_BF16(a, *(const bf16x8*)vp, o[hh][dt]);
            }
        }
        __builtin_amdgcn_s_setprio(0);
    }
#pragma unroll
    for (int hh = 0; hh < 2; ++hh) {
        int g = wv * 2 + hh;
#pragma unroll
        for (int dt = 0; dt < 4; ++dt)
#pragma unroll
            for (int r = 0; r < 4; ++r)
                atomicAdd(&out[(size_t)(b * 1024 + i0 + quad * 4 + r) * 1024 +
                               g * 64 + dt * 16 + l15], o[hh][dt][r]);
    }
}

extern "C" void kernel_launch(void* const* d_in, const int* in_sizes, int n_in,
                              void* d_out, int out_size, void* d_ws, size_t ws_size,
                              hipStream_t stream) {
    const float* x     = (const float*)d_in[0];
    const float* ctx   = (const float*)d_in[1];
    const float* Wq    = (const float*)d_in[2];
    const float* Wkv   = (const float*)d_in[3];
    const float* Wt    = (const float*)d_in[4];
    const float* gamma = (const float*)d_in[5];
    const float* beta  = (const float*)d_in[6];
    float* out = (float*)d_out;

    // ws layout (bf16 els): xb 4M | ctxb 4M | WqT 1M | WkvT 2M | Qb 4M | Kb 4M |
    //                       Vt 4M | L (64K fp32) | WtcT (512 bf16)
    bf16* xb   = (bf16*)d_ws;
    bf16* cb   = xb + (size_t)4 * 1024 * 1024;
    bf16* WqT  = cb + (size_t)4 * 1024 * 1024;
    bf16* WkvT = WqT + (size_t)1024 * 1024;
    bf16* Qb   = WkvT + (size_t)2048 * 1024;
    bf16* Kb   = Qb + (size_t)4 * 1024 * 1024;
    bf16* Vt   = Kb + (size_t)4 * 1024 * 1024;
    float* L   = (float*)(Vt + (size_t)4 * 1024 * 1024);
    bf16* WtcT = (bf16*)(L + (size_t)4 * 16 * 1024);

    prep_kernel<<<11328, 256, 0, stream>>>(x, ctx, Wq, Wkv, xb, cb, WqT, WkvT, out, L);
    gemm_all<<<768, 256, 0, stream>>>(xb, cb, WqT, WkvT, Qb, Kb, Vt);
    dv_kernel<<<2049, 256, 0, stream>>>(Qb, Kb, L, Wt, WtcT);
    attn_kernel<<<dim3(64, 4, 2), 512, 0, stream>>>(Qb, Kb, Vt, L, WtcT, gamma, beta, out);
}

// Round 17
// 316.763 us; speedup vs baseline: 1.0359x; 1.0185x over previous
//
#include <hip/hip_runtime.h>
#include <hip/hip_bf16.h>

typedef __bf16 bf16;
typedef bf16 bf16x2 __attribute__((ext_vector_type(2)));
typedef bf16 bf16x4 __attribute__((ext_vector_type(4)));
typedef bf16 bf16x8 __attribute__((ext_vector_type(8)));
typedef float floatx4 __attribute__((ext_vector_type(4)));

#define MFMA_BF16(a, b, c) __builtin_amdgcn_mfma_f32_16x16x32_bf16((a), (b), (c), 0, 0, 0)

// Async global->LDS DMA, 16 B per lane. LDS dest = uniform base + lane*16B
// (hardware rule, learn_hip m104); global src is per-lane.
__device__ __forceinline__ void gload16(const bf16* gsrc, bf16* ldst) {
    __builtin_amdgcn_global_load_lds(
        (__attribute__((address_space(1))) void*)const_cast<bf16*>(gsrc),
        (__attribute__((address_space(3))) void*)ldst,
        16, 0, 0);
}

// ---------------------------------------------------------------------------
// MERGED prep + zeroing (memsets folded in as block ranges):
//   blocks 0..4095     : cvt x/ctx -> bf16 (8 els/thread)
//   blocks 4096..7167  : weight transpose (Wq 1024 tiles, Wkv 2048 tiles)
//   blocks 7168..11263 : zero `out` (float4 stores)
//   blocks 11264..11327: zero `L`
// ---------------------------------------------------------------------------
__global__ __launch_bounds__(256) void prep_kernel(const float* __restrict__ x,
                                                   const float* __restrict__ ctx,
                                                   const float* __restrict__ Wq,
                                                   const float* __restrict__ Wkv,
                                                   bf16* __restrict__ xb,
                                                   bf16* __restrict__ cb,
                                                   bf16* __restrict__ WqT,
                                                   bf16* __restrict__ WkvT,
                                                   float* __restrict__ out,
                                                   float* __restrict__ L) {
    __shared__ float tile[32][33];
    const int t = threadIdx.x;
    int blk = blockIdx.x;
    if (blk >= 7168) {                      // ---- zeroing tasks ----
        if (blk < 11264) {                  // out: 4096 blocks * 256 * 4 floats
            int idx = (blk - 7168) * 256 + t;
            ((float4*)out)[idx] = make_float4(0.f, 0.f, 0.f, 0.f);
        } else {                            // L: 64 blocks * 256 * 4 floats
            int idx = (blk - 11264) * 256 + t;
            ((float4*)L)[idx] = make_float4(0.f, 0.f, 0.f, 0.f);
        }
        return;
    }
    if (blk < 4096) {                       // ---- cvt task ----
        int idx = blk * 256 + t;
        const float* in; bf16* outp;
        if (idx < 524288) { in = x; outp = xb; }
        else              { in = ctx; outp = cb; idx -= 524288; }
        const float* src = in + (size_t)idx * 8;
        float4 f0 = *(const float4*)src;
        float4 f1 = *(const float4*)(src + 4);
        bf16x8 v = {(bf16)f0.x, (bf16)f0.y, (bf16)f0.z, (bf16)f0.w,
                    (bf16)f1.x, (bf16)f1.y, (bf16)f1.z, (bf16)f1.w};
        *(bf16x8*)(outp + (size_t)idx * 8) = v;
        return;
    }
    blk -= 4096;                            // ---- transpose task ----
    const float* in; bf16* outp; int R, C, bx, by;
    if (blk < 1024) { in = Wq;  outp = WqT;  R = 1024; C = 1024; bx = blk & 31; by = blk >> 5; }
    else { blk -= 1024; in = Wkv; outp = WkvT; R = 1024; C = 2048; bx = blk & 63; by = blk >> 6; }
    const int r0 = by * 32, c0 = bx * 32;
    int r = t >> 3, c4 = (t & 7) * 4;
    float4 v = *(const float4*)&in[(size_t)(r0 + r) * C + c0 + c4];
    tile[r][c4 + 0] = v.x; tile[r][c4 + 1] = v.y;
    tile[r][c4 + 2] = v.z; tile[r][c4 + 3] = v.w;
    __syncthreads();
    int rp = t >> 3, cp = (t & 7) * 4;
    bf16x4 w = {(bf16)tile[cp + 0][rp], (bf16)tile[cp + 1][rp],
                (bf16)tile[cp + 2][rp], (bf16)tile[cp + 3][rp]};
    *(bf16x4*)&outp[(size_t)(c0 + rp) * R + r0 + cp] = w;
}

// ---------------------------------------------------------------------------
// MERGED GEMM with FUSED V-TRANSPOSE EPILOGUE — R13-identical (measured).
// ---------------------------------------------------------------------------
__global__ __launch_bounds__(256) void gemm_all(const bf16* __restrict__ xb,
                                                const bf16* __restrict__ cb,
                                                const bf16* __restrict__ WqT,
                                                const bf16* __restrict__ WkvT,
                                                bf16* __restrict__ Qb,
                                                bf16* __restrict__ Kb,
                                                bf16* __restrict__ Vt) {
    __shared__ bf16 As[128 * 32];
    __shared__ bf16 Bs[128 * 32];
    __shared__ __align__(16) bf16 Ts[64 * 136];   // [hd_local][j + 8 pad]
    const int t = threadIdx.x;
    const int wv = t >> 6, lane = t & 63, quad = lane >> 4, l15 = lane & 15;
    const int wr = wv >> 1, wc = wv & 1;
    unsigned nb = blockIdx.x;
    unsigned o = (nb & 7) * 96 + (nb >> 3);
    const bf16 *A, *B; bool kv; int bx, by;
    if (o < 256) { A = xb; B = WqT; kv = false; bx = o & 7; by = o >> 3; }
    else { unsigned ob = o - 256; A = cb; B = WkvT; kv = true; bx = ob & 15; by = ob >> 4; }
    const int m0 = by * 128, n0 = bx * 128;
    const int srow = lane >> 2, scol = (lane & 3) * 8;   // staging lane geometry

    floatx4 acc[4][4] = {};

    for (int k0 = 0; k0 < 1024; k0 += 32) {
        __syncthreads();          // previous iter's LDS reads complete
#pragma unroll
        for (int ri = 0; ri < 2; ++ri) {
            const int rb = (ri * 4 + wv) * 16;            // uniform per wave
            gload16(&A[(size_t)(m0 + rb + srow) * 1024 + k0 + scol], &As[rb * 32]);
            gload16(&B[(size_t)(n0 + rb + srow) * 1024 + k0 + scol], &Bs[rb * 32]);
        }
        __syncthreads();          // drains vmcnt(0): tiles ready
        bf16x8 af[4], bfr[4];
#pragma unroll
        for (int mt = 0; mt < 4; ++mt)
            af[mt] = *(bf16x8*)&As[(wr * 64 + mt * 16 + l15) * 32 + quad * 8];
#pragma unroll
        for (int nt = 0; nt < 4; ++nt)
            bfr[nt] = *(bf16x8*)&Bs[(wc * 64 + nt * 16 + l15) * 32 + quad * 8];
#pragma unroll
        for (int mt = 0; mt < 4; ++mt)
#pragma unroll
            for (int nt = 0; nt < 4; ++nt)
                acc[mt][nt] = MFMA_BF16(af[mt], bfr[nt], acc[mt][nt]);
    }

    if (!kv || n0 < 1024) {
        bf16* C = kv ? Kb : Qb;
#pragma unroll
        for (int mt = 0; mt < 4; ++mt)
#pragma unroll
            for (int nt = 0; nt < 4; ++nt)
#pragma unroll
                for (int r = 0; r < 4; ++r) {
                    int m = m0 + wr * 64 + mt * 16 + quad * 4 + r;
                    int n = n0 + wc * 64 + nt * 16 + l15;
                    C[(size_t)m * 1024 + n] = (bf16)acc[mt][nt][r];
                }
    } else {
        const int b = m0 >> 10, j0 = m0 & 1023, hd0 = n0 - 1024;
#pragma unroll
        for (int half = 0; half < 2; ++half) {
            __syncthreads();                    // seal prior Ts reads
            if (wc == half) {
#pragma unroll
                for (int mt = 0; mt < 4; ++mt)
#pragma unroll
                    for (int nt = 0; nt < 4; ++nt) {
                        int hdl = nt * 16 + l15;
                        int jl  = wr * 64 + mt * 16 + quad * 4;
                        bf16x4 p = {(bf16)acc[mt][nt][0], (bf16)acc[mt][nt][1],
                                    (bf16)acc[mt][nt][2], (bf16)acc[mt][nt][3]};
                        *(bf16x4*)&Ts[hdl * 136 + jl] = p;
                    }
            }
            __syncthreads();                    // Ts ready
#pragma unroll
            for (int k = 0; k < 4; ++k) {
                int idx = t + 256 * k;
                int row = idx >> 4, c8 = idx & 15;
                bf16x8 v = *(bf16x8*)&Ts[row * 136 + c8 * 8];
                *(bf16x8*)&Vt[(size_t)(b * 1024 + hd0 + half * 64 + row) * 1024 +
                              j0 + c8 * 8] = v;
            }
        }
    }
}

// ---------------------------------------------------------------------------
// MERGED denom + prep_wt — R13-identical.
// ---------------------------------------------------------------------------
__global__ __launch_bounds__(256, 4) void dv_kernel(const bf16* __restrict__ Qb,
                                                    const bf16* __restrict__ Kb,
                                                    float* __restrict__ L,
                                                    const float* __restrict__ Wt,
                                                    bf16* __restrict__ WtcT) {
    const int t = threadIdx.x;
    if (blockIdx.x == 2048) {                // ---- prep_wt task ----
        const int g = t >> 4, k = t & 15;
        float s = 0.f;
#pragma unroll
        for (int gg = 0; gg < 16; ++gg) s += Wt[k * 16 + gg];
        WtcT[g * 32 + k] = (bf16)(Wt[k * 16 + g] - s * 0.0625f);
        WtcT[g * 32 + 16 + k] = (bf16)0.f;
        return;
    }
    // ---- denom task ----
    const int wv = t >> 6, lane = t & 63, quad = lane >> 4, l15 = lane & 15;
    unsigned n = blockIdx.x;                               // 0..2047
    unsigned o = (n & 7) * 256 + (n >> 3);
    const int i0 = (o & 31) * 32;
    const int b  = (o >> 5) & 3;
    const int jz = o >> 7;
    const float scale = 0.125f;
    const bf16* Kbase = Kb + (size_t)b * 1024 * 1024;

    for (int hh = 0; hh < 4; ++hh) {
        const int h = wv * 4 + hh;
        bf16x8 qa[2][2];
#pragma unroll
        for (int it = 0; it < 2; ++it) {
            const bf16* qp = Qb + (size_t)(b * 1024 + i0 + it * 16 + l15) * 1024 +
                             h * 64 + quad * 8;
            qa[it][0] = *(const bf16x8*)qp;
            qa[it][1] = *(const bf16x8*)(qp + 32);
        }
        floatx4 se[2] = {};
#pragma unroll
        for (int jt = 0; jt < 4; ++jt) {
            int j = jz * 64 + jt * 16 + l15;
            const bf16* kp = Kbase + (size_t)j * 1024 + h * 64 + quad * 8;
            bf16x8 k0 = *(const bf16x8*)kp;
            bf16x8 k1 = *(const bf16x8*)(kp + 32);
#pragma unroll
            for (int it = 0; it < 2; ++it) {
                floatx4 c = {0.f, 0.f, 0.f, 0.f};
                c = MFMA_BF16(qa[it][0], k0, c);
                c = MFMA_BF16(qa[it][1], k1, c);
#pragma unroll
                for (int r = 0; r < 4; ++r) se[it][r] += __expf(c[r] * scale);
            }
        }
#pragma unroll
        for (int it = 0; it < 2; ++it)
#pragma unroll
            for (int r = 0; r < 4; ++r) {
                float s = se[it][r];
                s += __shfl_xor(s, 1); s += __shfl_xor(s, 2);
                s += __shfl_xor(s, 4); s += __shfl_xor(s, 8);
                if (l15 == 0)
                    atomicAdd(&L[(size_t)(b * 16 + h) * 1024 + i0 + it * 16 +
                                 quad * 4 + r], s);
            }
    }
}

// ---------------------------------------------------------------------------
// Main fused attention — R13-identical (measured 148.9 us):
// grid (64,4,2), 512 thr, 2 barriers/jt, LDS 40960 (rot-640 Buf2, zero-hole),
// XCD swizzle. VGPR 60 / SGPR 48, no spills.
// ---------------------------------------------------------------------------
__global__ __launch_bounds__(512, 4) void attn_kernel(const bf16* __restrict__ Qb,
                                                      const bf16* __restrict__ Kb,
                                                      const bf16* __restrict__ Vt,
                                                      const float* __restrict__ L,
                                                      const bf16* __restrict__ WtcT,
                                                      const float* __restrict__ gamma,
                                                      const float* __restrict__ beta,
                                                      float* __restrict__ out) {
    __shared__ bf16 Buf1[512 * 20];        // [point p=i*32+jl][16 h + 4 pad]
    __shared__ bf16 Buf2[16 * 640];        // [g][rot(g) + i*40 + jl]
    const int t = threadIdx.x;
    const int wv = t >> 6, lane = t & 63, quad = lane >> 4, l15 = lane & 15;
    unsigned n = blockIdx.x + (blockIdx.y << 6) + (blockIdx.z << 8);   // 512 total
    unsigned o_idx = (n & 7) * 64 + (n >> 3);
    const int i0 = (o_idx & 63) * 16;
    const int b  = (o_idx >> 6) & 3;
    const int jz = o_idx >> 8;
    const float scale = 0.125f;

    if (t < 8) Buf2[2560 + t] = (bf16)0.f;   // zero region in the rot-hole
    const bf16* Zbuf = &Buf2[2560];

    bf16x8 a_wt = *(const bf16x8*)&WtcT[l15 * 32 + quad * 8];
    float gq[4], bq[4];
#pragma unroll
    for (int r = 0; r < 4; ++r) { gq[r] = gamma[quad * 4 + r]; bq[r] = beta[quad * 4 + r]; }

    bf16x8 qa[2][2];
    float invl[2][4];
#pragma unroll
    for (int hh = 0; hh < 2; ++hh) {
        int h = wv * 2 + hh;
        const bf16* qp = Qb + (size_t)(b * 1024 + i0 + l15) * 1024 + h * 64 + quad * 8;
        qa[hh][0] = *(const bf16x8*)qp;
        qa[hh][1] = *(const bf16x8*)(qp + 32);
#pragma unroll
        for (int r = 0; r < 4; ++r)
            invl[hh][r] = 1.f / L[(size_t)(b * 16 + h) * 1024 + i0 + quad * 4 + r];
    }

    const bf16* Kbase = Kb + (size_t)b * 1024 * 1024;
    const bf16* Vbase = Vt + (size_t)b * 16 * 64 * 1024;
    floatx4 o[2][4] = {};

    for (int jt = 0; jt < 16; ++jt) {
        const int j0 = jz * 512 + jt * 32;
#pragma unroll
        for (int ns = 0; ns < 2; ++ns) {
            floatx4 cw[2];
#pragma unroll
            for (int hh = 0; hh < 2; ++hh) {
                int h = wv * 2 + hh;
                const bf16* kp = Kbase + (size_t)(j0 + ns * 16 + l15) * 1024 + h * 64 + quad * 8;
                floatx4 c = {0.f, 0.f, 0.f, 0.f};
                c = MFMA_BF16(qa[hh][0], *(const bf16x8*)kp, c);
                c = MFMA_BF16(qa[hh][1], *(const bf16x8*)(kp + 32), c);
                cw[hh] = c;
            }
#pragma unroll
            for (int r = 0; r < 4; ++r) {
                bf16x2 pk = {(bf16)(__expf(cw[0][r] * scale) * invl[0][r]),
                             (bf16)(__expf(cw[1][r] * scale) * invl[1][r])};
                *(bf16x2*)&Buf1[((quad * 4 + r) * 32 + ns * 16 + l15) * 20 + wv * 2] = pk;
            }
        }
        __syncthreads();
#pragma unroll
        for (int grp = 0; grp < 4; ++grp) {
            int gi = wv * 4 + grp, ig = gi >> 1, jb = (gi & 1) * 16;
            int p = ig * 32 + jb + l15;
            const bf16* src = (quad < 2) ? &Buf1[p * 20 + quad * 8] : Zbuf;
            floatx4 c = {0.f, 0.f, 0.f, 0.f};
            c = MFMA_BF16(a_wt, *(const bf16x8*)src, c);
            float s2 = c[0] * c[0] + c[1] * c[1] + c[2] * c[2] + c[3] * c[3];
            s2 += __shfl_xor(s2, 16);
            s2 += __shfl_xor(s2, 32);
            float rs = rsqrtf(s2 * 0.0625f + 1e-5f);
#pragma unroll
            for (int r = 0; r < 4; ++r) {
                float w2 = c[r] * rs * gq[r] + bq[r];
                Buf2[(quad * 4 + r) * 640 + (quad & 1) * 8 + ig * 40 + jb + l15] = (bf16)w2;
            }
        }
        __syncthreads();
#pragma unroll
        for (int hh = 0; hh < 2; ++hh) {
            int g = wv * 2 + hh;
            bf16x8 a = *(bf16x8*)&Buf2[g * 640 + ((g >> 2) & 1) * 8 + l15 * 40 + quad * 8];
#pragma unroll
            for (int dt = 0; dt < 4; ++dt) {
                const bf16* vp = Vbase + (size_t)(g * 64 + dt * 16 + l15) * 1024 + j0 + quad * 8;
                o[hh][dt] = MFMA_BF16(a, *(const bf16x8*)vp, o[hh][dt]);
            }
        }
    }
#pragma unroll
    for (int hh = 0; hh < 2; ++hh) {
        int g = wv * 2 + hh;
#pragma unroll
        for (int dt = 0; dt < 4; ++dt)
#pragma unroll
            for (int r = 0; r < 4; ++r)
                atomicAdd(&out[(size_t)(b * 1024 + i0 + quad * 4 + r) * 1024 +
                               g * 64 + dt * 16 + l15], o[hh][dt][r]);
    }
}

extern "C" void kernel_launch(void* const* d_in, const int* in_sizes, int n_in,
                              void* d_out, int out_size, void* d_ws, size_t ws_size,
                              hipStream_t stream) {
    const float* x     = (const float*)d_in[0];
    const float* ctx   = (const float*)d_in[1];
    const float* Wq    = (const float*)d_in[2];
    const float* Wkv   = (const float*)d_in[3];
    const float* Wt    = (const float*)d_in[4];
    const float* gamma = (const float*)d_in[5];
    const float* beta  = (const float*)d_in[6];
    float* out = (float*)d_out;

    // ws layout (bf16 els): xb 4M | ctxb 4M | WqT 1M | WkvT 2M | Qb 4M | Kb 4M |
    //                       Vt 4M | L (64K fp32) | WtcT (512 bf16)
    bf16* xb   = (bf16*)d_ws;
    bf16* cb   = xb + (size_t)4 * 1024 * 1024;
    bf16* WqT  = cb + (size_t)4 * 1024 * 1024;
    bf16* WkvT = WqT + (size_t)1024 * 1024;
    bf16* Qb   = WkvT + (size_t)2048 * 1024;
    bf16* Kb   = Qb + (size_t)4 * 1024 * 1024;
    bf16* Vt   = Kb + (size_t)4 * 1024 * 1024;
    float* L   = (float*)(Vt + (size_t)4 * 1024 * 1024);
    bf16* WtcT = (bf16*)(L + (size_t)4 * 16 * 1024);

    prep_kernel<<<11328, 256, 0, stream>>>(x, ctx, Wq, Wkv, xb, cb, WqT, WkvT, out, L);
    gemm_all<<<768, 256, 0, stream>>>(xb, cb, WqT, WkvT, Qb, Kb, Vt);
    dv_kernel<<<2049, 256, 0, stream>>>(Qb, Kb, L, Wt, WtcT);
    attn_kernel<<<dim3(64, 4, 2), 512, 0, stream>>>(Qb, Kb, Vt, L, WtcT, gamma, beta, out);
}